// Round 1
// baseline (122.450 us; speedup 1.0000x reference)
//
#include <hip/hip_runtime.h>
#include <hip/hip_bf16.h>

typedef unsigned short u16;
typedef unsigned int u32;
typedef __attribute__((ext_vector_type(8))) __bf16 bf16x8;
typedef __attribute__((ext_vector_type(4))) float f32x4;

#define NB 4       // batch
#define SQ 4096    // seq len
#define DM 1024    // d_model
#define RPC 4096   // rows per residue class (NB*SQ/4)

__device__ __forceinline__ u16 f2b(float f) {
  u32 u = __builtin_bit_cast(u32, f);
  u32 r = u + 0x7fffu + ((u >> 16) & 1u);
  return (u16)(r >> 16);
}
__device__ __forceinline__ float dot2(u32 q, u32 k) {
  float ql = __builtin_bit_cast(float, q << 16);
  float qh = __builtin_bit_cast(float, q & 0xffff0000u);
  float kl = __builtin_bit_cast(float, k << 16);
  float kh = __builtin_bit_cast(float, k & 0xffff0000u);
  return ql * kl + qh * kh;
}
__device__ __forceinline__ u32 mul2(u32 v, float p) {
  float lo = __builtin_bit_cast(float, v << 16) * p;
  float hi = __builtin_bit_cast(float, v & 0xffff0000u) * p;
  return (u32)f2b(lo) | ((u32)f2b(hi) << 16);
}

// ---- pack W{q,k,v} columns for class c, transposed to [768][1024] bf16 ----
// col(c, j): msel=j/256 picks matrix; slot=(j%256)/64; col=(c+4*slot)*64 + j%64
__global__ __launch_bounds__(256) void trans_qkv(const float* __restrict__ Wq,
                                                 const float* __restrict__ Wk,
                                                 const float* __restrict__ Wv,
                                                 u16* __restrict__ WT) {
  __shared__ float T[64][65];
  const int k0 = blockIdx.x * 64, j0 = blockIdx.y * 64, c = blockIdx.z;
  const int msel = j0 >> 8;
  const float* W = (msel == 0) ? Wq : ((msel == 1) ? Wk : Wv);
  const int slot = (j0 & 255) >> 6;
  const int colbase = (c + 4 * slot) * 64;
  const int tid = threadIdx.x;
  const int rr = tid >> 6, cc = tid & 63;
#pragma unroll
  for (int it = 0; it < 16; ++it) {
    const int kk = rr + it * 4;
    T[kk][cc] = W[(size_t)(k0 + kk) * 1024 + colbase + cc];
  }
  __syncthreads();
  u16* dst = WT + ((size_t)(c * 768 + j0) << 10) + k0;
#pragma unroll
  for (int it = 0; it < 16; ++it) {
    const int jj = rr + it * 4;
    dst[((size_t)jj << 10) + cc] = f2b(T[cc][jj]);
  }
}

// ---- pack Wo rows for class c, transposed to [1024][256] bf16 ----
// row(c, j) = c*64 + (j/64)*256 + j%64
__global__ __launch_bounds__(256) void trans_wo(const float* __restrict__ Wo,
                                                u16* __restrict__ WoT) {
  __shared__ float T[64][65];
  const int j0 = blockIdx.x * 64, e0 = blockIdx.y * 64, c = blockIdx.z;
  const int rowbase = c * 64 + (j0 >> 6) * 256;
  const int tid = threadIdx.x;
  const int rr = tid >> 6, cc = tid & 63;
#pragma unroll
  for (int it = 0; it < 16; ++it) {
    const int jj = rr + it * 4;
    T[jj][cc] = Wo[(size_t)(rowbase + jj) * 1024 + e0 + cc];
  }
  __syncthreads();
  u16* dst = WoT + ((size_t)(c * 1024) + e0) * 256 + j0;
#pragma unroll
  for (int it = 0; it < 16; ++it) {
    const int ee = rr + it * 4;
    dst[(size_t)ee * 256 + cc] = f2b(T[cc][ee]);
  }
}

__global__ __launch_bounds__(256) void bias_pack(const float* __restrict__ bq,
                                                 const float* __restrict__ bk,
                                                 const float* __restrict__ bv,
                                                 float* __restrict__ biasp) {
  const int idx = blockIdx.x * 256 + threadIdx.x;  // 4*768
  if (idx >= 3072) return;
  const int c = idx / 768, j = idx % 768;
  const int msel = j >> 8, jj = j & 255;
  const int col = (c + 4 * (jj >> 6)) * 64 + (jj & 63);
  const float* bb = (msel == 0) ? bq : ((msel == 1) ? bk : bv);
  biasp[idx] = bb[col];
}

// ---- GEMM1: per class, [4096 x 768] = x_rows(c) [4096 x 1024] @ WT^T ----
__global__ __launch_bounds__(256) void gemm_qkv(const float* __restrict__ x,
                                                const u16* __restrict__ WT,
                                                const float* __restrict__ biasp,
                                                u16* __restrict__ QKV) {
  __shared__ u16 As[128][40];
  __shared__ u16 Bs[128][40];
  const int c = blockIdx.z, m0 = blockIdx.y, n0 = blockIdx.x;
  const int tid = threadIdx.x;
  const int lane = tid & 63, w = tid >> 6;
  const int wm = w >> 1, wn = w & 1;
  const int l15 = lane & 15, l16 = lane >> 4;

  f32x4 acc[4][4];
#pragma unroll
  for (int i = 0; i < 4; ++i)
#pragma unroll
    for (int j = 0; j < 4; ++j) acc[i][j] = (f32x4){0.f, 0.f, 0.f, 0.f};

  const int rbase = m0 * 128;
  const int b = rbase >> 10;
  const int sbase = ((rbase & 1023) << 2) + c;
  const float* xA = x + (size_t)(b * SQ + sbase) * DM;
  const u16* WTc = WT + (size_t)(c * 768 + n0 * 128) * 1024;

  const int ai = tid >> 3, aq = tid & 7;
  const int bn = tid >> 2, bp = tid & 3;

  for (int k0 = 0; k0 < 1024; k0 += 32) {
    __syncthreads();
#pragma unroll
    for (int it = 0; it < 4; ++it) {
      const int i = ai + it * 32;
      float4 v = *reinterpret_cast<const float4*>(xA + (size_t)i * (4 * DM) + k0 + aq * 4);
      ushort4 pk;
      pk.x = f2b(v.x); pk.y = f2b(v.y); pk.z = f2b(v.z); pk.w = f2b(v.w);
      *reinterpret_cast<ushort4*>(&As[i][aq * 4]) = pk;
    }
#pragma unroll
    for (int it = 0; it < 2; ++it) {
      const int nn = bn + it * 64;
      *reinterpret_cast<uint4*>(&Bs[nn][bp * 8]) =
          *reinterpret_cast<const uint4*>(WTc + (size_t)nn * 1024 + k0 + bp * 8);
    }
    __syncthreads();
    bf16x8 af[4], bfr[4];
#pragma unroll
    for (int mf = 0; mf < 4; ++mf)
      af[mf] = *reinterpret_cast<const bf16x8*>(&As[wm * 64 + mf * 16 + l15][l16 * 8]);
#pragma unroll
    for (int nf = 0; nf < 4; ++nf)
      bfr[nf] = *reinterpret_cast<const bf16x8*>(&Bs[wn * 64 + nf * 16 + l15][l16 * 8]);
#pragma unroll
    for (int mf = 0; mf < 4; ++mf)
#pragma unroll
      for (int nf = 0; nf < 4; ++nf)
        acc[mf][nf] = __builtin_amdgcn_mfma_f32_16x16x32_bf16(af[mf], bfr[nf], acc[mf][nf], 0, 0, 0);
  }

  u16* outc = QKV + (size_t)c * RPC * 768;
#pragma unroll
  for (int mf = 0; mf < 4; ++mf) {
#pragma unroll
    for (int nf = 0; nf < 4; ++nf) {
      const int gcol = n0 * 128 + wn * 64 + nf * 16 + l15;
      const float bias = biasp[c * 768 + gcol];
#pragma unroll
      for (int jj = 0; jj < 4; ++jj) {
        const int rowt = wm * 64 + mf * 16 + l16 * 4 + jj;
        outc[(size_t)(rbase + rowt) * 768 + gcol] = f2b(acc[mf][nf][jj] + bias);
      }
    }
  }
}

// ---- attention: per (c,b,segment): 128 dilated positions, 4 head-slots ----
__global__ __launch_bounds__(256) void attn_k(const u16* __restrict__ QKV,
                                              u16* __restrict__ attnY) {
  __shared__ float sc[4][128];
  const int blk = blockIdx.x;
  const int c = blk >> 5, b = (blk >> 3) & 3, n = blk & 7;
  const int r0 = b * 1024 + n * 128;
  const u16* base = QKV + ((size_t)c * RPC + r0) * 768;
  const int tid = threadIdx.x;
#pragma unroll
  for (int it = 0; it < 2; ++it) {
    const int tt = tid + it * 256;
    const int t = tt & 127, slot = tt >> 7;
    const u16* q = base + (size_t)t * 768 + slot * 64;
    float s = 0.f;
#pragma unroll
    for (int dd = 0; dd < 8; ++dd) {
      uint4 qa = *reinterpret_cast<const uint4*>(q + dd * 8);
      uint4 ka = *reinterpret_cast<const uint4*>(q + 256 + dd * 8);
      s += dot2(qa.x, ka.x) + dot2(qa.y, ka.y) + dot2(qa.z, ka.z) + dot2(qa.w, ka.w);
    }
    sc[slot][t] = s * 0.125f;  // hd^-0.5 = 1/8
  }
  __syncthreads();
  const int w = tid >> 6, lane = tid & 63;
  float v0 = sc[w][lane], v1 = sc[w][lane + 64];
  float m = fmaxf(v0, v1);
#pragma unroll
  for (int off = 32; off; off >>= 1) m = fmaxf(m, __shfl_xor(m, off));
  float e0 = __expf(v0 - m), e1 = __expf(v1 - m);
  float ssum = e0 + e1;
#pragma unroll
  for (int off = 32; off; off >>= 1) ssum += __shfl_xor(ssum, off);
  const float inv = 1.f / ssum;
  sc[w][lane] = e0 * inv;
  sc[w][lane + 64] = e1 * inv;
  __syncthreads();
  u16* yout = attnY + ((size_t)c * RPC + r0) * 256;
#pragma unroll
  for (int it = 0; it < 16; ++it) {
    const int vi = tid + it * 256;
    const int t = vi >> 5, c8 = vi & 31;
    const float p = sc[c8 >> 3][t];
    uint4 va = *reinterpret_cast<const uint4*>(base + (size_t)t * 768 + 512 + c8 * 8);
    uint4 ra;
    ra.x = mul2(va.x, p); ra.y = mul2(va.y, p); ra.z = mul2(va.z, p); ra.w = mul2(va.w, p);
    *reinterpret_cast<uint4*>(yout + (size_t)t * 256 + c8 * 8) = ra;
  }
}

// ---- GEMM2: per class, out_rows(c) [4096 x 1024] = attnY [4096 x 256] @ Wo_sel ----
__global__ __launch_bounds__(256) void gemm_out(const u16* __restrict__ attnY,
                                                const u16* __restrict__ WoT,
                                                const float* __restrict__ bo,
                                                float* __restrict__ out) {
  __shared__ u16 As[128][40];
  __shared__ u16 Bs[128][40];
  const int c = blockIdx.z, m0 = blockIdx.y, n0 = blockIdx.x;
  const int tid = threadIdx.x;
  const int lane = tid & 63, w = tid >> 6;
  const int wm = w >> 1, wn = w & 1;
  const int l15 = lane & 15, l16 = lane >> 4;

  f32x4 acc[4][4];
#pragma unroll
  for (int i = 0; i < 4; ++i)
#pragma unroll
    for (int j = 0; j < 4; ++j) acc[i][j] = (f32x4){0.f, 0.f, 0.f, 0.f};

  const int rbase = m0 * 128;
  const u16* Ac = attnY + ((size_t)c * RPC + rbase) * 256;
  const u16* Bc = WoT + (size_t)(c * 1024 + n0 * 128) * 256;
  const int ai = tid >> 2, ap = tid & 3;

  for (int k0 = 0; k0 < 256; k0 += 32) {
    __syncthreads();
#pragma unroll
    for (int it = 0; it < 2; ++it) {
      const int i = ai + it * 64;
      *reinterpret_cast<uint4*>(&As[i][ap * 8]) =
          *reinterpret_cast<const uint4*>(Ac + (size_t)i * 256 + k0 + ap * 8);
      *reinterpret_cast<uint4*>(&Bs[i][ap * 8]) =
          *reinterpret_cast<const uint4*>(Bc + (size_t)i * 256 + k0 + ap * 8);
    }
    __syncthreads();
    bf16x8 af[4], bfr[4];
#pragma unroll
    for (int mf = 0; mf < 4; ++mf)
      af[mf] = *reinterpret_cast<const bf16x8*>(&As[wm * 64 + mf * 16 + l15][l16 * 8]);
#pragma unroll
    for (int nf = 0; nf < 4; ++nf)
      bfr[nf] = *reinterpret_cast<const bf16x8*>(&Bs[wn * 64 + nf * 16 + l15][l16 * 8]);
#pragma unroll
    for (int mf = 0; mf < 4; ++mf)
#pragma unroll
      for (int nf = 0; nf < 4; ++nf)
        acc[mf][nf] = __builtin_amdgcn_mfma_f32_16x16x32_bf16(af[mf], bfr[nf], acc[mf][nf], 0, 0, 0);
  }

  const int b = rbase >> 10;
  const int sbase = ((rbase & 1023) << 2) + c;
  float* outp = out + (size_t)(b * SQ + sbase) * DM;
#pragma unroll
  for (int mf = 0; mf < 4; ++mf) {
#pragma unroll
    for (int nf = 0; nf < 4; ++nf) {
      const int gcol = n0 * 128 + wn * 64 + nf * 16 + l15;
      const float bias = bo[gcol];
#pragma unroll
      for (int jj = 0; jj < 4; ++jj) {
        const int rowt = wm * 64 + mf * 16 + l16 * 4 + jj;
        outp[(size_t)rowt * (4 * DM) + gcol] = acc[mf][nf][jj] + bias;
      }
    }
  }
}

extern "C" void kernel_launch(void* const* d_in, const int* in_sizes, int n_in,
                              void* d_out, int out_size, void* d_ws, size_t ws_size,
                              hipStream_t stream) {
  const float* x  = (const float*)d_in[0];
  const float* Wq = (const float*)d_in[1];
  const float* bq = (const float*)d_in[2];
  const float* Wk = (const float*)d_in[3];
  const float* bk = (const float*)d_in[4];
  const float* Wv = (const float*)d_in[5];
  const float* bv = (const float*)d_in[6];
  const float* Wo = (const float*)d_in[7];
  const float* bo = (const float*)d_in[8];
  float* out = (float*)d_out;

  char* ws = (char*)d_ws;
  u16*   WT    = (u16*)(ws);                    // 4*768*1024*2   = 6,291,456
  float* biasp = (float*)(ws + 6291456);        // 4*768*4        = 12,288
  u16*   WoT   = (u16*)(ws + 6303744);          // 4*1024*256*2   = 2,097,152
  u16*   QKV   = (u16*)(ws + 8400896);          // 4*4096*768*2   = 25,165,824
  u16*   attnY = (u16*)(ws + 33566720);         // 4*4096*256*2   = 8,388,608

  trans_qkv<<<dim3(16, 12, 4), 256, 0, stream>>>(Wq, Wk, Wv, WT);
  bias_pack<<<12, 256, 0, stream>>>(bq, bk, bv, biasp);
  trans_wo<<<dim3(4, 16, 4), 256, 0, stream>>>(Wo, WoT);
  gemm_qkv<<<dim3(6, 32, 4), 256, 0, stream>>>(x, WT, biasp, QKV);
  attn_k<<<128, 256, 0, stream>>>(QKV, attnY);
  gemm_out<<<dim3(8, 32, 4), 256, 0, stream>>>(attnY, WoT, bo, out);
}

// Round 2
// 99.212 us; speedup vs baseline: 1.2342x; 1.2342x over previous
//
#include <hip/hip_runtime.h>
#include <hip/hip_bf16.h>

typedef unsigned short u16;
typedef unsigned int u32;
typedef __attribute__((ext_vector_type(8))) __bf16 bf16x8;
typedef __attribute__((ext_vector_type(4))) float f32x4;

#define NB 4       // batch
#define SQ 4096    // seq len
#define DM 1024    // d_model
#define RPC 4096   // rows per residue class (NB*SQ/4)

__device__ __forceinline__ u16 f2b(float f) {
  u32 u = __builtin_bit_cast(u32, f);
  u32 r = u + 0x7fffu + ((u >> 16) & 1u);
  return (u16)(r >> 16);
}
__device__ __forceinline__ u32 cvt2(float lo, float hi) {
  u16 a = __builtin_bit_cast(u16, __float2bfloat16(lo));
  u16 b = __builtin_bit_cast(u16, __float2bfloat16(hi));
  return (u32)a | ((u32)b << 16);
}
__device__ __forceinline__ float dot2(u32 q, u32 k) {
  float ql = __builtin_bit_cast(float, q << 16);
  float qh = __builtin_bit_cast(float, q & 0xffff0000u);
  float kl = __builtin_bit_cast(float, k << 16);
  float kh = __builtin_bit_cast(float, k & 0xffff0000u);
  return ql * kl + qh * kh;
}
__device__ __forceinline__ u32 mul2(u32 v, float p) {
  float lo = __builtin_bit_cast(float, v << 16) * p;
  float hi = __builtin_bit_cast(float, v & 0xffff0000u) * p;
  return (u32)f2b(lo) | ((u32)f2b(hi) << 16);
}
__device__ __forceinline__ void gll16(const void* g, void* l) {
  __builtin_amdgcn_global_load_lds(
      (const __attribute__((address_space(1))) void*)g,
      (__attribute__((address_space(3))) void*)l, 16, 0, 0);
}

// ---- pack W{q,k,v} for class c into swizzled LDS-image tiles ----
// B^T panel per class: [768 rows(N)][1024 cols(K)]; tiles BN=256 x BK=64.
// image u16 idx = ((c*3+n0)*16 + k64)*16384 + nrow*64 + p*8 + e, p = u ^ (nrow&7)
__global__ __launch_bounds__(256) void trans_qkv(const float* __restrict__ Wq,
                                                 const float* __restrict__ Wk,
                                                 const float* __restrict__ Wv,
                                                 u16* __restrict__ WTp) {
  __shared__ float T[64][65];
  const int k0 = blockIdx.x * 64, j0 = blockIdx.y * 64, c = blockIdx.z;
  const int msel = j0 >> 8;
  const float* W = (msel == 0) ? Wq : ((msel == 1) ? Wk : Wv);
  const int slot = (j0 & 255) >> 6;
  const int colbase = (c + 4 * slot) * 64;
  const int tid = threadIdx.x;
  const int rr = tid >> 6, cc = tid & 63;
#pragma unroll
  for (int it = 0; it < 16; ++it) {
    const int kk = rr + it * 4;
    T[kk][cc] = W[(size_t)(k0 + kk) * 1024 + colbase + cc];
  }
  __syncthreads();
  const int k64 = k0 >> 6;
  const int u = cc >> 3, e = cc & 7;
#pragma unroll
  for (int it = 0; it < 16; ++it) {
    const int jj = rr + it * 4;
    const int j = j0 + jj;
    const int n0 = j >> 8, nrow = j & 255;
    const int p = u ^ (nrow & 7);
    WTp[((size_t)((c * 3 + n0) * 16 + k64)) * 16384 + nrow * 64 + p * 8 + e] = f2b(T[cc][jj]);
  }
}

// ---- pack Wo for class c into swizzled tiles: B^T [1024(N)][256(K)], BN=128 x BK=64
__global__ __launch_bounds__(256) void trans_wo(const float* __restrict__ Wo,
                                                u16* __restrict__ WoTp) {
  __shared__ float T[64][65];
  const int j0 = blockIdx.x * 64, e0 = blockIdx.y * 64, c = blockIdx.z;
  const int rowbase = c * 64 + (j0 >> 6) * 256;
  const int tid = threadIdx.x;
  const int rr = tid >> 6, cc = tid & 63;
#pragma unroll
  for (int it = 0; it < 16; ++it) {
    const int jj = rr + it * 4;
    T[jj][cc] = Wo[(size_t)(rowbase + jj) * 1024 + e0 + cc];
  }
  __syncthreads();
  const int k64 = j0 >> 6;
  const int u = cc >> 3, e = cc & 7;
#pragma unroll
  for (int it = 0; it < 16; ++it) {
    const int ee = rr + it * 4;
    const int n = e0 + ee;
    const int n0 = n >> 7, nrow = n & 127;
    const int p = u ^ (nrow & 7);
    WoTp[((size_t)((c * 8 + n0) * 4 + k64)) * 8192 + nrow * 64 + p * 8 + e] = f2b(T[cc][ee]);
  }
}

__global__ __launch_bounds__(256) void bias_pack(const float* __restrict__ bq,
                                                 const float* __restrict__ bk,
                                                 const float* __restrict__ bv,
                                                 float* __restrict__ biasp) {
  const int idx = blockIdx.x * 256 + threadIdx.x;  // 4*768
  if (idx >= 3072) return;
  const int c = idx / 768, j = idx % 768;
  const int msel = j >> 8, jj = j & 255;
  const int col = (c + 4 * (jj >> 6)) * 64 + (jj & 63);
  const float* bb = (msel == 0) ? bq : ((msel == 1) ? bk : bv);
  biasp[idx] = bb[col];
}

// ---- GEMM1: per class, [4096 x 768] = x_rows(c)[4096 x 1024] @ WTp^T ----
// BM=128, BN=256, BK=64; 4 waves, wave tile 64x128.
__global__ __launch_bounds__(256, 2) void gemm_qkv(const float* __restrict__ x,
                                                   const u16* __restrict__ WTp,
                                                   const float* __restrict__ biasp,
                                                   u16* __restrict__ QKV) {
  __shared__ __align__(16) u16 As[8192];   // 128 x 64, swizzled
  __shared__ __align__(16) u16 Bs[16384];  // 256 x 64, swizzled
  const int c = blockIdx.z, m0 = blockIdx.y, n0 = blockIdx.x;
  const int tid = threadIdx.x;
  const int lane = tid & 63, w = tid >> 6;
  const int wm = w >> 1, wn = w & 1;
  const int l15 = lane & 15, l16 = lane >> 4;

  f32x4 acc[4][8];
#pragma unroll
  for (int i = 0; i < 4; ++i)
#pragma unroll
    for (int j = 0; j < 8; ++j) acc[i][j] = (f32x4){0.f, 0.f, 0.f, 0.f};

  const int rbase = m0 * 128;
  const int b = rbase >> 10;
  const int sbase = ((rbase & 1023) << 2) + c;
  const float* xA = x + (size_t)(b * SQ + sbase) * DM;  // row stride 4*DM

  const int arow = tid >> 3, au = tid & 7;
  int awoff[4];
#pragma unroll
  for (int w4 = 0; w4 < 4; ++w4) {
    const int row = w4 * 32 + arow;
    awoff[w4] = row * 64 + ((au ^ (row & 7)) << 3);
  }
  const u16* Bsrc = WTp + (size_t)((c * 3 + n0) * 16) * 16384 + tid * 8;
  char* BsW = (char*)Bs + w * 1024;

  int aoff[2][4], boff[2][8];
#pragma unroll
  for (int kk = 0; kk < 2; ++kk) {
    const int unit = kk * 4 + l16;
#pragma unroll
    for (int mf = 0; mf < 4; ++mf) {
      const int row = wm * 64 + mf * 16 + l15;
      aoff[kk][mf] = row * 64 + ((unit ^ (row & 7)) << 3);
    }
#pragma unroll
    for (int nf = 0; nf < 8; ++nf) {
      const int row = wn * 128 + nf * 16 + l15;
      boff[kk][nf] = row * 64 + ((unit ^ (row & 7)) << 3);
    }
  }

  float4 av[8];
#pragma unroll
  for (int w4 = 0; w4 < 4; ++w4) {
    const float* s = xA + (size_t)(w4 * 32 + arow) * (4 * DM) + au * 8;
    av[2 * w4] = *reinterpret_cast<const float4*>(s);
    av[2 * w4 + 1] = *reinterpret_cast<const float4*>(s + 4);
  }

#pragma unroll 1
  for (int k64 = 0; k64 < 16; ++k64) {
    __syncthreads();
#pragma unroll
    for (int it = 0; it < 8; ++it)
      gll16(Bsrc + (size_t)k64 * 16384 + it * 2048, BsW + it * 4096);
#pragma unroll
    for (int w4 = 0; w4 < 4; ++w4) {
      uint4 pk;
      pk.x = cvt2(av[2 * w4].x, av[2 * w4].y);
      pk.y = cvt2(av[2 * w4].z, av[2 * w4].w);
      pk.z = cvt2(av[2 * w4 + 1].x, av[2 * w4 + 1].y);
      pk.w = cvt2(av[2 * w4 + 1].z, av[2 * w4 + 1].w);
      *reinterpret_cast<uint4*>(&As[awoff[w4]]) = pk;
    }
    __syncthreads();
    if (k64 < 15) {
      const int k0 = (k64 + 1) * 64;
#pragma unroll
      for (int w4 = 0; w4 < 4; ++w4) {
        const float* s = xA + (size_t)(w4 * 32 + arow) * (4 * DM) + k0 + au * 8;
        av[2 * w4] = *reinterpret_cast<const float4*>(s);
        av[2 * w4 + 1] = *reinterpret_cast<const float4*>(s + 4);
      }
    }
#pragma unroll
    for (int kk = 0; kk < 2; ++kk) {
      bf16x8 af[4], bv[8];
#pragma unroll
      for (int mf = 0; mf < 4; ++mf) af[mf] = *reinterpret_cast<const bf16x8*>(&As[aoff[kk][mf]]);
#pragma unroll
      for (int nf = 0; nf < 8; ++nf) bv[nf] = *reinterpret_cast<const bf16x8*>(&Bs[boff[kk][nf]]);
#pragma unroll
      for (int mf = 0; mf < 4; ++mf)
#pragma unroll
        for (int nf = 0; nf < 8; ++nf)
          acc[mf][nf] = __builtin_amdgcn_mfma_f32_16x16x32_bf16(af[mf], bv[nf], acc[mf][nf], 0, 0, 0);
    }
  }

  u16* outc = QKV + (size_t)c * RPC * 768;
#pragma unroll
  for (int mf = 0; mf < 4; ++mf) {
#pragma unroll
    for (int nf = 0; nf < 8; ++nf) {
      const int gcol = n0 * 256 + wn * 128 + nf * 16 + l15;
      const float bias = biasp[c * 768 + gcol];
#pragma unroll
      for (int jj = 0; jj < 4; ++jj) {
        const int rowt = wm * 64 + mf * 16 + l16 * 4 + jj;
        outc[(size_t)(rbase + rowt) * 768 + gcol] = f2b(acc[mf][nf][jj] + bias);
      }
    }
  }
}

// ---- attention: per (c,b,segment): 128 dilated positions, 4 head-slots ----
// writes attnY in swizzled LDS-image tile format for gemm_out A staging.
__global__ __launch_bounds__(256) void attn_k(const u16* __restrict__ QKV,
                                              u16* __restrict__ attnYp) {
  __shared__ float sc[4][128];
  const int blk = blockIdx.x;
  const int c = blk >> 5, b = (blk >> 3) & 3, n = blk & 7;
  const int r0 = b * 1024 + n * 128;
  const int m0 = b * 8 + n;
  const u16* base = QKV + ((size_t)c * RPC + r0) * 768;
  const int tid = threadIdx.x;
#pragma unroll
  for (int it = 0; it < 2; ++it) {
    const int tt = tid + it * 256;
    const int t = tt & 127, slot = tt >> 7;
    const u16* q = base + (size_t)t * 768 + slot * 64;
    float s = 0.f;
#pragma unroll
    for (int dd = 0; dd < 8; ++dd) {
      uint4 qa = *reinterpret_cast<const uint4*>(q + dd * 8);
      uint4 ka = *reinterpret_cast<const uint4*>(q + 256 + dd * 8);
      s += dot2(qa.x, ka.x) + dot2(qa.y, ka.y) + dot2(qa.z, ka.z) + dot2(qa.w, ka.w);
    }
    sc[slot][t] = s * 0.125f;  // hd^-0.5 = 1/8
  }
  __syncthreads();
  const int w = tid >> 6, lane = tid & 63;
  float v0 = sc[w][lane], v1 = sc[w][lane + 64];
  float m = fmaxf(v0, v1);
#pragma unroll
  for (int off = 32; off; off >>= 1) m = fmaxf(m, __shfl_xor(m, off));
  float e0 = __expf(v0 - m), e1 = __expf(v1 - m);
  float ssum = e0 + e1;
#pragma unroll
  for (int off = 32; off; off >>= 1) ssum += __shfl_xor(ssum, off);
  const float inv = 1.f / ssum;
  sc[w][lane] = e0 * inv;
  sc[w][lane + 64] = e1 * inv;
  __syncthreads();
  u16* yout = attnYp + (size_t)((c * 32 + m0) * 4) * 8192;
#pragma unroll
  for (int it = 0; it < 16; ++it) {
    const int vi = tid + it * 256;
    const int t = vi >> 5, c8 = vi & 31;
    const float p = sc[c8 >> 3][t];
    uint4 va = *reinterpret_cast<const uint4*>(base + (size_t)t * 768 + 512 + c8 * 8);
    uint4 ra;
    ra.x = mul2(va.x, p); ra.y = mul2(va.y, p); ra.z = mul2(va.z, p); ra.w = mul2(va.w, p);
    const int k64 = c8 >> 3, uu = c8 & 7, pp = uu ^ (t & 7);
    *reinterpret_cast<uint4*>(yout + k64 * 8192 + t * 64 + pp * 8) = ra;
  }
}

// ---- GEMM2: per class, out_rows(c)[4096 x 1024] = attnY[4096 x 256] @ Wo_sel ----
// BM=128, BN=128, BK=64; both operands via global_load_lds from swizzled tiles.
__global__ __launch_bounds__(256) void gemm_out(const u16* __restrict__ attnYp,
                                                const u16* __restrict__ WoTp,
                                                const float* __restrict__ bo,
                                                float* __restrict__ out) {
  __shared__ __align__(16) u16 As[8192];
  __shared__ __align__(16) u16 Bs[8192];
  const int c = blockIdx.z, m0 = blockIdx.y, n0 = blockIdx.x;
  const int tid = threadIdx.x;
  const int lane = tid & 63, w = tid >> 6;
  const int wm = w >> 1, wn = w & 1;
  const int l15 = lane & 15, l16 = lane >> 4;

  f32x4 acc[4][4];
#pragma unroll
  for (int i = 0; i < 4; ++i)
#pragma unroll
    for (int j = 0; j < 4; ++j) acc[i][j] = (f32x4){0.f, 0.f, 0.f, 0.f};

  const u16* Asrc = attnYp + (size_t)((c * 32 + m0) * 4) * 8192 + tid * 8;
  const u16* Bsrc = WoTp + (size_t)((c * 8 + n0) * 4) * 8192 + tid * 8;
  char* AsW = (char*)As + w * 1024;
  char* BsW = (char*)Bs + w * 1024;

  int aoff[2][4], boff[2][4];
#pragma unroll
  for (int kk = 0; kk < 2; ++kk) {
    const int unit = kk * 4 + l16;
#pragma unroll
    for (int f = 0; f < 4; ++f) {
      const int ra = wm * 64 + f * 16 + l15;
      aoff[kk][f] = ra * 64 + ((unit ^ (ra & 7)) << 3);
      const int rb = wn * 64 + f * 16 + l15;
      boff[kk][f] = rb * 64 + ((unit ^ (rb & 7)) << 3);
    }
  }

#pragma unroll 1
  for (int k64 = 0; k64 < 4; ++k64) {
    __syncthreads();
#pragma unroll
    for (int it = 0; it < 4; ++it) {
      gll16(Asrc + (size_t)k64 * 8192 + it * 2048, AsW + it * 4096);
      gll16(Bsrc + (size_t)k64 * 8192 + it * 2048, BsW + it * 4096);
    }
    __syncthreads();
#pragma unroll
    for (int kk = 0; kk < 2; ++kk) {
      bf16x8 af[4], bfv[4];
#pragma unroll
      for (int f = 0; f < 4; ++f) {
        af[f] = *reinterpret_cast<const bf16x8*>(&As[aoff[kk][f]]);
        bfv[f] = *reinterpret_cast<const bf16x8*>(&Bs[boff[kk][f]]);
      }
#pragma unroll
      for (int mf = 0; mf < 4; ++mf)
#pragma unroll
        for (int nf = 0; nf < 4; ++nf)
          acc[mf][nf] = __builtin_amdgcn_mfma_f32_16x16x32_bf16(af[mf], bfv[nf], acc[mf][nf], 0, 0, 0);
    }
  }

  const int rbase = m0 * 128;
  const int b = rbase >> 10;
  const int sbase = ((rbase & 1023) << 2) + c;
  float* outp = out + (size_t)(b * SQ + sbase) * DM;
#pragma unroll
  for (int mf = 0; mf < 4; ++mf) {
#pragma unroll
    for (int nf = 0; nf < 4; ++nf) {
      const int gcol = n0 * 128 + wn * 64 + nf * 16 + l15;
      const float bias = bo[gcol];
#pragma unroll
      for (int jj = 0; jj < 4; ++jj) {
        const int rowt = wm * 64 + mf * 16 + l16 * 4 + jj;
        outp[(size_t)rowt * (4 * DM) + gcol] = acc[mf][nf][jj] + bias;
      }
    }
  }
}

extern "C" void kernel_launch(void* const* d_in, const int* in_sizes, int n_in,
                              void* d_out, int out_size, void* d_ws, size_t ws_size,
                              hipStream_t stream) {
  const float* x  = (const float*)d_in[0];
  const float* Wq = (const float*)d_in[1];
  const float* bq = (const float*)d_in[2];
  const float* Wk = (const float*)d_in[3];
  const float* bk = (const float*)d_in[4];
  const float* Wv = (const float*)d_in[5];
  const float* bv = (const float*)d_in[6];
  const float* Wo = (const float*)d_in[7];
  const float* bo = (const float*)d_in[8];
  float* out = (float*)d_out;

  char* ws = (char*)d_ws;
  u16*   WTp   = (u16*)(ws);                    // 4*3*16*16384*2 = 6,291,456
  float* biasp = (float*)(ws + 6291456);        // 4*768*4        = 12,288
  u16*   WoTp  = (u16*)(ws + 6303744);          // 4*8*4*8192*2   = 2,097,152
  u16*   QKV   = (u16*)(ws + 8400896);          // 4*4096*768*2   = 25,165,824
  u16*   attnYp= (u16*)(ws + 33566720);         // 4*32*4*8192*2  = 8,388,608

  trans_qkv<<<dim3(16, 12, 4), 256, 0, stream>>>(Wq, Wk, Wv, WTp);
  bias_pack<<<12, 256, 0, stream>>>(bq, bk, bv, biasp);
  trans_wo<<<dim3(4, 16, 4), 256, 0, stream>>>(Wo, WoTp);
  gemm_qkv<<<dim3(3, 32, 4), 256, 0, stream>>>(x, WTp, biasp, QKV);
  attn_k<<<128, 256, 0, stream>>>(QKV, attnYp);
  gemm_out<<<dim3(8, 32, 4), 256, 0, stream>>>(attnYp, WoTp, bo, out);
}

// Round 3
// 84.045 us; speedup vs baseline: 1.4569x; 1.1805x over previous
//
#include <hip/hip_runtime.h>
#include <hip/hip_bf16.h>

typedef unsigned short u16;
typedef unsigned int u32;
typedef __attribute__((ext_vector_type(8))) __bf16 bf16x8;
typedef __attribute__((ext_vector_type(4))) float f32x4;

#define NB 4       // batch
#define SQ 4096    // seq len
#define DM 1024    // d_model
#define RPC 4096   // rows per residue class (NB*SQ/4)
#define S4 (4 * DM)

#define VMCNT(n) asm volatile("s_waitcnt vmcnt(" #n ")" ::: "memory")
#define LGKM0()  asm volatile("s_waitcnt lgkmcnt(0)" ::: "memory")
#define BARRIER() asm volatile("s_barrier" ::: "memory")

__device__ __forceinline__ u16 f2b(float f) {
  u32 u = __builtin_bit_cast(u32, f);
  u32 r = u + 0x7fffu + ((u >> 16) & 1u);
  return (u16)(r >> 16);
}
__device__ __forceinline__ u32 cvt2(float lo, float hi) {
  u16 a = __builtin_bit_cast(u16, __float2bfloat16(lo));
  u16 b = __builtin_bit_cast(u16, __float2bfloat16(hi));
  return (u32)a | ((u32)b << 16);
}
__device__ __forceinline__ float dot2(u32 q, u32 k) {
  float ql = __builtin_bit_cast(float, q << 16);
  float qh = __builtin_bit_cast(float, q & 0xffff0000u);
  float kl = __builtin_bit_cast(float, k << 16);
  float kh = __builtin_bit_cast(float, k & 0xffff0000u);
  return ql * kl + qh * kh;
}
__device__ __forceinline__ u32 mul2(u32 v, float p) {
  float lo = __builtin_bit_cast(float, v << 16) * p;
  float hi = __builtin_bit_cast(float, v & 0xffff0000u) * p;
  return (u32)f2b(lo) | ((u32)f2b(hi) << 16);
}
__device__ __forceinline__ void gll16(const void* g, void* l) {
  __builtin_amdgcn_global_load_lds(
      (const __attribute__((address_space(1))) void*)g,
      (__attribute__((address_space(3))) void*)l, 16, 0, 0);
}

// ---- pack W{q,k,v} for class c into swizzled LDS-image tiles ----
// B^T panel per class: [768 N][1024 K]; tiles BN=192 x BK=64.
// u16 idx = ((c*4+n0)*16 + k64)*12288 + nrow*64 + ((u ^ (nrow&7))<<3) + e
__global__ __launch_bounds__(256) void trans_qkv(const float* __restrict__ Wq,
                                                 const float* __restrict__ Wk,
                                                 const float* __restrict__ Wv,
                                                 u16* __restrict__ WTp) {
  __shared__ float T[64][65];
  const int k0 = blockIdx.x * 64, j0 = blockIdx.y * 64, c = blockIdx.z;
  const int msel = j0 >> 8;
  const float* W = (msel == 0) ? Wq : ((msel == 1) ? Wk : Wv);
  const int slot = (j0 & 255) >> 6;
  const int colbase = (c + 4 * slot) * 64;
  const int tid = threadIdx.x;
  const int rr = tid >> 6, cc = tid & 63;
#pragma unroll
  for (int it = 0; it < 16; ++it) {
    const int kk = rr + it * 4;
    T[kk][cc] = W[(size_t)(k0 + kk) * 1024 + colbase + cc];
  }
  __syncthreads();
  const int k64 = k0 >> 6;
  const int u = cc >> 3, e = cc & 7;
#pragma unroll
  for (int it = 0; it < 16; ++it) {
    const int jj = rr + it * 4;
    const int j = j0 + jj;
    const int n0 = j / 192, nrow = j - n0 * 192;
    WTp[((size_t)((c * 4 + n0) * 16 + k64)) * 12288 + nrow * 64 + (((u ^ (nrow & 7))) << 3) + e] =
        f2b(T[cc][jj]);
  }
}

// ---- pack Wo for class c: B^T [1024 N][256 K], tiles BN=256 x BK=64 ----
// u16 idx = ((c*4+n0)*4 + k64)*16384 + nrow*64 + ((u ^ (nrow&7))<<3) + e
__global__ __launch_bounds__(256) void trans_wo(const float* __restrict__ Wo,
                                                u16* __restrict__ WoTp) {
  __shared__ float T[64][65];
  const int j0 = blockIdx.x * 64, e0 = blockIdx.y * 64, c = blockIdx.z;
  const int rowbase = c * 64 + (j0 >> 6) * 256;
  const int tid = threadIdx.x;
  const int rr = tid >> 6, cc = tid & 63;
#pragma unroll
  for (int it = 0; it < 16; ++it) {
    const int jj = rr + it * 4;
    T[jj][cc] = Wo[(size_t)(rowbase + jj) * 1024 + e0 + cc];
  }
  __syncthreads();
  const int k64 = j0 >> 6;
  const int u = cc >> 3, e = cc & 7;
#pragma unroll
  for (int it = 0; it < 16; ++it) {
    const int ee = rr + it * 4;
    const int n = e0 + ee;
    const int n0 = n >> 8, nrow = n & 255;
    WoTp[((size_t)((c * 4 + n0) * 4 + k64)) * 16384 + nrow * 64 + (((u ^ (nrow & 7))) << 3) + e] =
        f2b(T[cc][ee]);
  }
}

__global__ __launch_bounds__(256) void bias_pack(const float* __restrict__ bq,
                                                 const float* __restrict__ bk,
                                                 const float* __restrict__ bv,
                                                 float* __restrict__ biasp) {
  const int idx = blockIdx.x * 256 + threadIdx.x;  // 4*768
  if (idx >= 3072) return;
  const int c = idx / 768, j = idx % 768;
  const int msel = j >> 8, jj = j & 255;
  const int col = (c + 4 * (jj >> 6)) * 64 + (jj & 63);
  const float* bb = (msel == 0) ? bq : ((msel == 1) ? bk : bv);
  biasp[idx] = bb[col];
}

// ---- GEMM1: per class, [4096 x 768] = x_rows(c)[4096 x 1024] @ WTp^T ----
// BM=256, BN=192, BK=64; 8 waves (4Mx2N), wave tile 64x96.
// Drain-free counted-vmcnt pipeline: B via global_load_lds (2 tiles ahead),
// A via reg-stage fp32->bf16 (issue 3 ahead, ds_write 2 ahead).
__global__ __launch_bounds__(512, 2) void gemm_qkv(const float* __restrict__ x,
                                                   const u16* __restrict__ WTp,
                                                   const float* __restrict__ biasp,
                                                   u16* __restrict__ QKV) {
  __shared__ __align__(16) u16 As[2][16384];  // 256x64 bf16, swizzled
  __shared__ __align__(16) u16 Bs[2][12288];  // 192x64 bf16, swizzled
  const int p = blockIdx.x;
  const int L = (p & 7) * 32 + (p >> 3);  // XCD-contiguous logical id
  const int c = L >> 6, rem = L & 63;
  const int m0 = rem >> 2, n0 = rem & 3;
  const int tid = threadIdx.x;
  const int lane = tid & 63, w = tid >> 6;
  const int wm = w >> 1, wn = w & 1;
  const int l15 = lane & 15, l16 = lane >> 4;

  const int rbase = m0 * 256;
  const int b = rbase >> 10;
  const int sbase = ((rbase & 1023) << 2) + c;
  const float* xA = x + (size_t)(b * SQ + sbase) * DM;  // row stride S4

  // A staging: thread handles rows (tid>>3)+64j, cols (tid&7)*8..+7 of k-tile
  int awoff[4];
  const float* aptr[4];
#pragma unroll
  for (int j = 0; j < 4; ++j) {
    const int r = (tid >> 3) + 64 * j;
    awoff[j] = r * 64 + (((tid & 7) ^ (r & 7)) << 3);
    aptr[j] = xA + (size_t)r * S4 + (tid & 7) * 8;
  }
  const u16* Bsrc = WTp + (size_t)((c * 4 + n0) * 16) * 12288;

  f32x4 acc[4][6];
#pragma unroll
  for (int i = 0; i < 4; ++i)
#pragma unroll
    for (int j = 0; j < 6; ++j) acc[i][j] = (f32x4){0.f, 0.f, 0.f, 0.f};

  int aoff[2][4], boff[2][6];
#pragma unroll
  for (int kk = 0; kk < 2; ++kk) {
    const int unit = kk * 4 + l16;
#pragma unroll
    for (int mf = 0; mf < 4; ++mf) {
      const int r = wm * 64 + mf * 16 + l15;
      aoff[kk][mf] = r * 64 + ((unit ^ (r & 7)) << 3);
    }
#pragma unroll
    for (int nf = 0; nf < 6; ++nf) {
      const int r = wn * 96 + nf * 16 + l15;
      boff[kk][nf] = r * 64 + ((unit ^ (r & 7)) << 3);
    }
  }

  float4 av[8];

#define LOADA(kt)                                                          \
  {                                                                        \
    _Pragma("unroll") for (int j = 0; j < 4; ++j) {                        \
      const float* s = aptr[j] + (kt) * 64;                                \
      av[2 * j] = *reinterpret_cast<const float4*>(s);                     \
      av[2 * j + 1] = *reinterpret_cast<const float4*>(s + 4);             \
    }                                                                      \
  }
#define DSWRITE(buf)                                                       \
  {                                                                        \
    _Pragma("unroll") for (int j = 0; j < 4; ++j) {                        \
      uint4 pk;                                                            \
      pk.x = cvt2(av[2 * j].x, av[2 * j].y);                               \
      pk.y = cvt2(av[2 * j].z, av[2 * j].w);                               \
      pk.z = cvt2(av[2 * j + 1].x, av[2 * j + 1].y);                       \
      pk.w = cvt2(av[2 * j + 1].z, av[2 * j + 1].w);                       \
      *reinterpret_cast<uint4*>(&As[buf][awoff[j]]) = pk;                  \
    }                                                                      \
  }
#define ISSUE_B(kt, buf)                                                   \
  {                                                                        \
    _Pragma("unroll") for (int i = 0; i < 3; ++i)                          \
        gll16(Bsrc + (size_t)(kt) * 12288 + tid * 8 + i * 4096,            \
              (char*)&Bs[buf][0] + tid * 16 + i * 8192);                   \
  }

  // ---- prologue ----
  LOADA(0);
  DSWRITE(0);
  LOADA(1);
  ISSUE_B(0, 0);
  ISSUE_B(1, 1);
  VMCNT(6);   // av(1) complete (oldest 8 retired)
  DSWRITE(1);
  LOADA(2);
  VMCNT(8);   // B(0),B(1) complete; av(2) may remain in flight
  LGKM0();
  BARRIER();

  // ---- main loop: 16 K-tiles ----
#pragma unroll 1
  for (int t = 0; t < 16; ++t) {
    const u16* Ab = As[t & 1];
    const u16* Bb = Bs[t & 1];
#pragma unroll
    for (int kk = 0; kk < 2; ++kk) {
      bf16x8 af[4], bv[6];
#pragma unroll
      for (int mf = 0; mf < 4; ++mf) af[mf] = *reinterpret_cast<const bf16x8*>(Ab + aoff[kk][mf]);
#pragma unroll
      for (int nf = 0; nf < 6; ++nf) bv[nf] = *reinterpret_cast<const bf16x8*>(Bb + boff[kk][nf]);
      __builtin_amdgcn_s_setprio(1);
#pragma unroll
      for (int mf = 0; mf < 4; ++mf)
#pragma unroll
        for (int nf = 0; nf < 6; ++nf)
          acc[mf][nf] = __builtin_amdgcn_mfma_f32_16x16x32_bf16(af[mf], bv[nf], acc[mf][nf], 0, 0, 0);
      __builtin_amdgcn_s_setprio(0);
    }
    if (t == 15) break;
    BARRIER();  // reads of tile t done chip-wide; buf t&1 dead
    if (t <= 13) {
      VMCNT(8);            // B(t+1) complete
      ISSUE_B(t + 2, t & 1);
      VMCNT(3);            // av(t+2) complete (B(t+2) may remain)
      DSWRITE(t & 1);      // A(t+2) -> LDS
      if (t <= 12) LOADA(t + 3);
    } else {
      VMCNT(0);            // tail: B(15) complete
    }
    LGKM0();
    BARRIER();
  }

  // ---- epilogue: bias + bf16 store ----
  u16* outc = QKV + (size_t)c * RPC * 768;
#pragma unroll
  for (int mf = 0; mf < 4; ++mf) {
#pragma unroll
    for (int nf = 0; nf < 6; ++nf) {
      const int gcol = n0 * 192 + wn * 96 + nf * 16 + l15;
      const float bias = biasp[c * 768 + gcol];
#pragma unroll
      for (int jj = 0; jj < 4; ++jj) {
        const int rowt = wm * 64 + mf * 16 + l16 * 4 + jj;
        outc[(size_t)(rbase + rowt) * 768 + gcol] = f2b(acc[mf][nf][jj] + bias);
      }
    }
  }
#undef LOADA
#undef DSWRITE
#undef ISSUE_B
}

// ---- attention: per (c,b,segment,half): diagonal scores + softmax + p*V ----
// writes attnY in swizzled 256x64 tile images for gemm_out A staging.
__global__ __launch_bounds__(256) void attn_k(const u16* __restrict__ QKV,
                                              u16* __restrict__ attnYp) {
  __shared__ float sc[4][128];
  const int blk = blockIdx.x;  // 256
  const int c = blk >> 6, b = (blk >> 4) & 3, n = (blk >> 1) & 7, half = blk & 1;
  const int r0 = b * 1024 + n * 128;
  const int m0 = r0 >> 8;
  const int rb = r0 & 255;
  const u16* base = QKV + ((size_t)c * RPC + r0) * 768;
  const int tid = threadIdx.x;
#pragma unroll
  for (int it = 0; it < 2; ++it) {
    const int tt = tid + it * 256;
    const int t = tt & 127, slot = tt >> 7;
    const u16* q = base + (size_t)t * 768 + slot * 64;
    float s = 0.f;
#pragma unroll
    for (int dd = 0; dd < 8; ++dd) {
      uint4 qa = *reinterpret_cast<const uint4*>(q + dd * 8);
      uint4 ka = *reinterpret_cast<const uint4*>(q + 256 + dd * 8);
      s += dot2(qa.x, ka.x) + dot2(qa.y, ka.y) + dot2(qa.z, ka.z) + dot2(qa.w, ka.w);
    }
    sc[slot][t] = s * 0.125f;
  }
  __syncthreads();
  const int w = tid >> 6, lane = tid & 63;
  float v0 = sc[w][lane], v1 = sc[w][lane + 64];
  float m = fmaxf(v0, v1);
#pragma unroll
  for (int off = 32; off; off >>= 1) m = fmaxf(m, __shfl_xor(m, off));
  float e0 = __expf(v0 - m), e1 = __expf(v1 - m);
  float ssum = e0 + e1;
#pragma unroll
  for (int off = 32; off; off >>= 1) ssum += __shfl_xor(ssum, off);
  const float inv = 1.f / ssum;
  sc[w][lane] = e0 * inv;
  sc[w][lane + 64] = e1 * inv;
  __syncthreads();
  u16* yout = attnYp + (size_t)((c * 16 + m0) * 4) * 16384;
#pragma unroll
  for (int it = 0; it < 8; ++it) {
    const int vi = tid + it * 256;
    const int t = vi >> 4, c8 = (vi & 15) + half * 16;
    const float pr = sc[c8 >> 3][t];
    uint4 va = *reinterpret_cast<const uint4*>(base + (size_t)t * 768 + 512 + c8 * 8);
    uint4 ra;
    ra.x = mul2(va.x, pr); ra.y = mul2(va.y, pr); ra.z = mul2(va.z, pr); ra.w = mul2(va.w, pr);
    const int rloc = rb + t;
    const int k64 = c8 >> 3, uu = c8 & 7, pp = uu ^ (rloc & 7);
    *reinterpret_cast<uint4*>(yout + k64 * 16384 + rloc * 64 + pp * 8) = ra;
  }
}

// ---- GEMM2: per class, out_rows(c)[4096 x 1024] = attnY[4096 x 256] @ Wo ----
// BM=256, BN=256, BK=64 (4 K-tiles); both operands gll16 from swizzled images.
__global__ __launch_bounds__(512, 2) void gemm_out(const u16* __restrict__ attnYp,
                                                   const u16* __restrict__ WoTp,
                                                   const float* __restrict__ bo,
                                                   float* __restrict__ out) {
  __shared__ __align__(16) u16 As[2][16384];
  __shared__ __align__(16) u16 Bs[2][16384];
  const int p = blockIdx.x;
  const int L = (p & 7) * 32 + (p >> 3);
  const int c = L >> 6, rem = L & 63;
  const int m0 = rem >> 2, n0 = rem & 3;
  const int tid = threadIdx.x;
  const int lane = tid & 63, w = tid >> 6;
  const int wm = w >> 1, wn = w & 1;
  const int l15 = lane & 15, l16 = lane >> 4;

  const u16* Asrc = attnYp + (size_t)((c * 16 + m0) * 4) * 16384;
  const u16* Bsrc = WoTp + (size_t)((c * 4 + n0) * 4) * 16384;

  f32x4 acc[4][8];
#pragma unroll
  for (int i = 0; i < 4; ++i)
#pragma unroll
    for (int j = 0; j < 8; ++j) acc[i][j] = (f32x4){0.f, 0.f, 0.f, 0.f};

  int aoff[2][4], boff[2][8];
#pragma unroll
  for (int kk = 0; kk < 2; ++kk) {
    const int unit = kk * 4 + l16;
#pragma unroll
    for (int mf = 0; mf < 4; ++mf) {
      const int r = wm * 64 + mf * 16 + l15;
      aoff[kk][mf] = r * 64 + ((unit ^ (r & 7)) << 3);
    }
#pragma unroll
    for (int nf = 0; nf < 8; ++nf) {
      const int r = wn * 128 + nf * 16 + l15;
      boff[kk][nf] = r * 64 + ((unit ^ (r & 7)) << 3);
    }
  }

#define ISSUE(kt, buf)                                                     \
  {                                                                        \
    _Pragma("unroll") for (int i = 0; i < 4; ++i) {                        \
      gll16(Asrc + (size_t)(kt) * 16384 + tid * 8 + i * 4096,              \
            (char*)&As[buf][0] + tid * 16 + i * 8192);                     \
      gll16(Bsrc + (size_t)(kt) * 16384 + tid * 8 + i * 4096,              \
            (char*)&Bs[buf][0] + tid * 16 + i * 8192);                     \
    }                                                                      \
  }

  ISSUE(0, 0);
  ISSUE(1, 1);
  VMCNT(8);   // tile 0 complete
  BARRIER();

#pragma unroll 1
  for (int t = 0; t < 4; ++t) {
    const u16* Ab = As[t & 1];
    const u16* Bb = Bs[t & 1];
#pragma unroll
    for (int kk = 0; kk < 2; ++kk) {
      bf16x8 af[4], bv[8];
#pragma unroll
      for (int mf = 0; mf < 4; ++mf) af[mf] = *reinterpret_cast<const bf16x8*>(Ab + aoff[kk][mf]);
#pragma unroll
      for (int nf = 0; nf < 8; ++nf) bv[nf] = *reinterpret_cast<const bf16x8*>(Bb + boff[kk][nf]);
      __builtin_amdgcn_s_setprio(1);
#pragma unroll
      for (int mf = 0; mf < 4; ++mf)
#pragma unroll
        for (int nf = 0; nf < 8; ++nf)
          acc[mf][nf] = __builtin_amdgcn_mfma_f32_16x16x32_bf16(af[mf], bv[nf], acc[mf][nf], 0, 0, 0);
      __builtin_amdgcn_s_setprio(0);
    }
    if (t == 3) break;
    BARRIER();
    if (t <= 1) {
      ISSUE(t + 2, t & 1);
      VMCNT(8);  // tile t+1 complete, tile t+2 in flight
    } else {
      VMCNT(0);  // tail
    }
    BARRIER();
  }
#undef ISSUE

  const int rbase = m0 * 256;
  const int b = rbase >> 10;
  const int sbase = ((rbase & 1023) << 2) + c;
  float* outp = out + (size_t)(b * SQ + sbase) * DM;
#pragma unroll
  for (int mf = 0; mf < 4; ++mf) {
#pragma unroll
    for (int nf = 0; nf < 8; ++nf) {
      const int gcol = n0 * 256 + wn * 128 + nf * 16 + l15;
      const float bias = bo[gcol];
#pragma unroll
      for (int jj = 0; jj < 4; ++jj) {
        const int rowt = wm * 64 + mf * 16 + l16 * 4 + jj;
        outp[(size_t)rowt * S4 + gcol] = acc[mf][nf][jj] + bias;
      }
    }
  }
}

extern "C" void kernel_launch(void* const* d_in, const int* in_sizes, int n_in,
                              void* d_out, int out_size, void* d_ws, size_t ws_size,
                              hipStream_t stream) {
  const float* x  = (const float*)d_in[0];
  const float* Wq = (const float*)d_in[1];
  const float* bq = (const float*)d_in[2];
  const float* Wk = (const float*)d_in[3];
  const float* bk = (const float*)d_in[4];
  const float* Wv = (const float*)d_in[5];
  const float* bv = (const float*)d_in[6];
  const float* Wo = (const float*)d_in[7];
  const float* bo = (const float*)d_in[8];
  float* out = (float*)d_out;

  char* ws = (char*)d_ws;
  u16*   WTp   = (u16*)(ws);                    // 4*4*16*12288*2 = 6,291,456
  float* biasp = (float*)(ws + 6291456);        // 4*768*4        = 12,288
  u16*   WoTp  = (u16*)(ws + 6303744);          // 4*4*4*16384*2  = 2,097,152
  u16*   QKV   = (u16*)(ws + 8400896);          // 4*4096*768*2   = 25,165,824
  u16*   attnYp= (u16*)(ws + 33566720);         // 4*16*4*16384*2 = 8,388,608

  trans_qkv<<<dim3(16, 12, 4), 256, 0, stream>>>(Wq, Wk, Wv, WTp);
  bias_pack<<<12, 256, 0, stream>>>(bq, bk, bv, biasp);
  trans_wo<<<dim3(4, 16, 4), 256, 0, stream>>>(Wo, WoTp);
  gemm_qkv<<<256, 512, 0, stream>>>(x, WTp, biasp, QKV);
  attn_k<<<256, 256, 0, stream>>>(QKV, attnYp);
  gemm_out<<<256, 512, 0, stream>>>(attnYp, WoTp, bo, out);
}